// Round 1
// baseline (2052.862 us; speedup 1.0000x reference)
//
#include <hip/hip_runtime.h>

#define HID 128
#define HEADS 8
#define PHD 16
#define NE 250000
#define NT 3
#define TOTE (NT * NE)
#define NNODES 50000
#define EB 16                 // edges per wave (register-level W reuse factor)
#define NWAVES 4
#define EPB (EB * NWAVES)     // 64 edges per block

// NOTE: EB=16 divides NE=250000 and TOTE=750000, so every resident wave has a
// full batch of 16 edges, all of the same type. No per-edge guards needed.

// ---------------- Kernel 1: scores -> exp(s) per edge + sumexp per (node,head)
__global__ __launch_bounds__(256)
void score_kernel(const float* __restrict__ x,
                  const int* __restrict__ adj0,
                  const int* __restrict__ adj1,
                  const int* __restrict__ adj2,
                  const float* __restrict__ Wq,
                  const float* __restrict__ Wk,
                  float* __restrict__ sumexp,
                  float* __restrict__ expS)
{
    __shared__ __align__(16) float rowS[NWAVES][EB][HID];
    __shared__ __align__(16) float rowT[NWAVES][EB][HID];
    const int tid  = threadIdx.x;
    const int wave = tid >> 6;
    const int lane = tid & 63;
    const int base = blockIdx.x * EPB + wave * EB;   // global edge id of batch start
    if (base >= TOTE) return;
    const int t  = base / NE;                        // wave-uniform edge type
    const int eb = base - t * NE;                    // index within type
    const int* __restrict__ adj = (t == 0) ? adj0 : (t == 1) ? adj1 : adj2;
    const float* __restrict__ Wq_t = Wq + t * HID * HID;
    const float* __restrict__ Wk_t = Wk + t * HID * HID;
    const int j0 = lane * 2;                         // this lane's 2 output cols

    int tgts[EB];
    #pragma unroll
    for (int e = 0; e < EB; ++e) {
        const int s  = adj[2 * (eb + e)];
        const int tg = adj[2 * (eb + e) + 1];
        tgts[e] = tg;
        *(float2*)&rowS[wave][e][j0] = *(const float2*)(x + s  * HID + j0);
        *(float2*)&rowT[wave][e][j0] = *(const float2*)(x + tg * HID + j0);
    }
    // wave-local LDS use only: compiler-inserted lgkmcnt waits suffice, no barrier.

    float qa0[EB], qa1[EB], ka0[EB], ka1[EB];
    #pragma unroll
    for (int e = 0; e < EB; ++e) { qa0[e] = qa1[e] = ka0[e] = ka1[e] = 0.f; }

    for (int c = 0; c < HID; c += 4) {
        float2 wq[4], wk[4];
        #pragma unroll
        for (int u = 0; u < 4; ++u) {
            wq[u] = *(const float2*)(Wq_t + (c + u) * HID + j0);
            wk[u] = *(const float2*)(Wk_t + (c + u) * HID + j0);
        }
        #pragma unroll
        for (int e = 0; e < EB; ++e) {
            const float4 tv = *(const float4*)&rowT[wave][e][c];  // broadcast read
            const float4 sv = *(const float4*)&rowS[wave][e][c];
            qa0[e] += tv.x * wq[0].x; qa1[e] += tv.x * wq[0].y;
            qa0[e] += tv.y * wq[1].x; qa1[e] += tv.y * wq[1].y;
            qa0[e] += tv.z * wq[2].x; qa1[e] += tv.z * wq[2].y;
            qa0[e] += tv.w * wq[3].x; qa1[e] += tv.w * wq[3].y;
            ka0[e] += sv.x * wk[0].x; ka1[e] += sv.x * wk[0].y;
            ka0[e] += sv.y * wk[1].x; ka1[e] += sv.y * wk[1].y;
            ka0[e] += sv.z * wk[2].x; ka1[e] += sv.z * wk[2].y;
            ka0[e] += sv.w * wk[3].x; ka1[e] += sv.w * wk[3].y;
        }
    }

    // s[h] = scale * sum_{j in head h} q[j]*k[j]; lane owns j=2l,2l+1; head = l>>3
    #pragma unroll
    for (int e = 0; e < EB; ++e) {
        float d = (qa0[e] * ka0[e] + qa1[e] * ka1[e]) * 0.25f;  // scale = PHD^-0.5
        d += __shfl_xor(d, 1);
        d += __shfl_xor(d, 2);
        d += __shfl_xor(d, 4);
        if ((lane & 7) == 0) {
            const int h = lane >> 3;
            const float ex = __expf(d);       // |s| ~ O(1): no max-shift needed
            expS[(base + e) * 8 + h] = ex;
            unsafeAtomicAdd(&sumexp[tgts[e] * 8 + h], ex);
        }
    }
}

// ---------------- Kernel 2: messages + prob-weighted scatter-add
__global__ __launch_bounds__(256)
void agg_kernel(const float* __restrict__ x,
                const int* __restrict__ adj0,
                const int* __restrict__ adj1,
                const int* __restrict__ adj2,
                const float* __restrict__ Wm,
                const float* __restrict__ bm,
                const float* __restrict__ sumexp,
                const float* __restrict__ expS,
                float* __restrict__ out)
{
    __shared__ __align__(16) float rowS[NWAVES][EB][HID];
    __shared__ __align__(16) float rowT[NWAVES][EB][HID];
    const int tid  = threadIdx.x;
    const int wave = tid >> 6;
    const int lane = tid & 63;
    const int base = blockIdx.x * EPB + wave * EB;
    if (base >= TOTE) return;
    const int t  = base / NE;
    const int eb = base - t * NE;
    const int* __restrict__ adj = (t == 0) ? adj0 : (t == 1) ? adj1 : adj2;
    const float* __restrict__ Wm_t = Wm + t * 2 * HID * HID;
    const float* __restrict__ bm_t = bm + t * HID;
    const int j0 = lane * 2;

    int tgts[EB];
    #pragma unroll
    for (int e = 0; e < EB; ++e) {
        const int s  = adj[2 * (eb + e)];
        const int tg = adj[2 * (eb + e) + 1];
        tgts[e] = tg;
        *(float2*)&rowS[wave][e][j0] = *(const float2*)(x + s  * HID + j0);
        *(float2*)&rowT[wave][e][j0] = *(const float2*)(x + tg * HID + j0);
    }

    float ma0[EB], ma1[EB];
    #pragma unroll
    for (int e = 0; e < EB; ++e) { ma0[e] = ma1[e] = 0.f; }

    // pair = [src_row (rows 0..127) , tgt_row (rows 128..255)] @ Wm
    for (int c = 0; c < HID; c += 4) {
        float2 wm[4];
        #pragma unroll
        for (int u = 0; u < 4; ++u)
            wm[u] = *(const float2*)(Wm_t + (c + u) * HID + j0);
        #pragma unroll
        for (int e = 0; e < EB; ++e) {
            const float4 sv = *(const float4*)&rowS[wave][e][c];
            ma0[e] += sv.x * wm[0].x; ma1[e] += sv.x * wm[0].y;
            ma0[e] += sv.y * wm[1].x; ma1[e] += sv.y * wm[1].y;
            ma0[e] += sv.z * wm[2].x; ma1[e] += sv.z * wm[2].y;
            ma0[e] += sv.w * wm[3].x; ma1[e] += sv.w * wm[3].y;
        }
    }
    for (int c = 0; c < HID; c += 4) {
        float2 wm[4];
        #pragma unroll
        for (int u = 0; u < 4; ++u)
            wm[u] = *(const float2*)(Wm_t + (HID + c + u) * HID + j0);
        #pragma unroll
        for (int e = 0; e < EB; ++e) {
            const float4 tv = *(const float4*)&rowT[wave][e][c];
            ma0[e] += tv.x * wm[0].x; ma1[e] += tv.x * wm[0].y;
            ma0[e] += tv.y * wm[1].x; ma1[e] += tv.y * wm[1].y;
            ma0[e] += tv.z * wm[2].x; ma1[e] += tv.z * wm[2].y;
            ma0[e] += tv.w * wm[3].x; ma1[e] += tv.w * wm[3].y;
        }
    }

    const float b0 = bm_t[j0];
    const float b1 = bm_t[j0 + 1];
    const int h = lane >> 3;
    #pragma unroll
    for (int e = 0; e < EB; ++e) {
        const float pe = expS[(base + e) * 8 + h];
        const float se = sumexp[tgts[e] * 8 + h];   // > 0: this edge contributed
        const float p  = pe / se;
        const float m0 = fmaxf(ma0[e] + b0, 0.f);
        const float m1 = fmaxf(ma1[e] + b1, 0.f);
        float* o = out + tgts[e] * HID + j0;
        unsafeAtomicAdd(o,     p * m0);
        unsafeAtomicAdd(o + 1, p * m1);
    }
}

extern "C" void kernel_launch(void* const* d_in, const int* in_sizes, int n_in,
                              void* d_out, int out_size, void* d_ws, size_t ws_size,
                              hipStream_t stream)
{
    const float* x   = (const float*)d_in[0];
    const int* adj0  = (const int*)d_in[1];
    const int* adj1  = (const int*)d_in[2];
    const int* adj2  = (const int*)d_in[3];
    const float* Wq  = (const float*)d_in[4];
    const float* Wk  = (const float*)d_in[5];
    const float* Wm  = (const float*)d_in[6];
    const float* bm  = (const float*)d_in[7];
    float* out = (float*)d_out;

    // ws layout: sumexp [NNODES*8 f32] | expS [TOTE*8 f32]  (total ~25.6 MB)
    float* sumexp = (float*)d_ws;
    float* expS   = sumexp + (size_t)NNODES * 8;

    hipMemsetAsync(out,    0, (size_t)NNODES * HID * sizeof(float), stream);
    hipMemsetAsync(sumexp, 0, (size_t)NNODES * 8 * sizeof(float), stream);

    const int nblk = (TOTE + EPB - 1) / EPB;
    score_kernel<<<nblk, 256, 0, stream>>>(x, adj0, adj1, adj2, Wq, Wk, sumexp, expS);
    agg_kernel<<<nblk, 256, 0, stream>>>(x, adj0, adj1, adj2, Wm, bm, sumexp, expS, out);
}

// Round 2
// 1039.936 us; speedup vs baseline: 1.9740x; 1.9740x over previous
//
#include <hip/hip_runtime.h>
#include <hip/hip_bf16.h>

#define HID 128
#define NE 250000
#define NT 3
#define NNODES 50000
#define EPW 16   // edges per wave in edge pass

typedef unsigned int uint32;

__device__ __forceinline__ unsigned short f2bf(float f) {
    uint32 u = __float_as_uint(f);
    u += 0x7fffu + ((u >> 16) & 1u);       // RNE (values finite)
    return (unsigned short)(u >> 16);
}
__device__ __forceinline__ float bflo(uint32 u) { return __uint_as_float(u << 16); }
__device__ __forceinline__ float bfhi(uint32 u) { return __uint_as_float(u & 0xffff0000u); }

// ---------------- K1: node-side projections, P[m][n][c] bf16, m in {q,k,a,b}
// out[row][col] = sum_c x[row][c] * W[c][col]  (+ bm for m==3)
__global__ __launch_bounds__(256)
void precompute_kernel(const float* __restrict__ x,
                       const float* __restrict__ Wq,
                       const float* __restrict__ Wk,
                       const float* __restrict__ Wm,
                       const float* __restrict__ bm,
                       unsigned short* __restrict__ P,   // 4 planes of 50000x128
                       int t)
{
    __shared__ __align__(16) float xs[64][HID];          // 32 KB
    const int tid = threadIdx.x;
    const int n0  = blockIdx.x * 64;
    const int m   = blockIdx.y;                          // 0=q 1=k 2=a(top) 3=b(bot+bias)

    {   // stage 64 node rows
        int r = tid >> 5;
        const int c = (tid & 31) * 4;
        for (; r < 64; r += 8)
            if (n0 + r < NNODES)
                *(float4*)&xs[r][c] = *(const float4*)(x + (size_t)(n0 + r) * HID + c);
    }
    __syncthreads();

    const int wave = tid >> 6;
    const int lane = tid & 63;
    const int r0   = wave * 16 + (lane >> 5) * 8;        // 8 rows per half-wave
    const int c4   = (lane & 31) * 4;                    // 4 cols per lane

    const float* Wbase;
    if (m == 0)      Wbase = Wq + (size_t)t * HID * HID;
    else if (m == 1) Wbase = Wk + (size_t)t * HID * HID;
    else if (m == 2) Wbase = Wm + (size_t)t * 2 * HID * HID;
    else             Wbase = Wm + (size_t)t * 2 * HID * HID + (size_t)HID * HID;

    float acc[8][4];
    #pragma unroll
    for (int r = 0; r < 8; ++r) { acc[r][0] = acc[r][1] = acc[r][2] = acc[r][3] = 0.f; }

    for (int c = 0; c < HID; c += 4) {
        float4 w[4];
        #pragma unroll
        for (int u = 0; u < 4; ++u)
            w[u] = *(const float4*)(Wbase + (size_t)(c + u) * HID + c4);
        #pragma unroll
        for (int r = 0; r < 8; ++r) {
            const float4 xv = *(const float4*)&xs[r0 + r][c];   // broadcast-ish (half-wave)
            acc[r][0] += xv.x * w[0].x + xv.y * w[1].x + xv.z * w[2].x + xv.w * w[3].x;
            acc[r][1] += xv.x * w[0].y + xv.y * w[1].y + xv.z * w[2].y + xv.w * w[3].y;
            acc[r][2] += xv.x * w[0].z + xv.y * w[1].z + xv.z * w[2].z + xv.w * w[3].z;
            acc[r][3] += xv.x * w[0].w + xv.y * w[1].w + xv.z * w[2].w + xv.w * w[3].w;
        }
    }

    if (m == 3) {   // fold bias into Pb
        const float4 bv = *(const float4*)(bm + (size_t)t * HID + c4);
        #pragma unroll
        for (int r = 0; r < 8; ++r) {
            acc[r][0] += bv.x; acc[r][1] += bv.y; acc[r][2] += bv.z; acc[r][3] += bv.w;
        }
    }

    unsigned short* Pm = P + (size_t)m * NNODES * HID;
    #pragma unroll
    for (int r = 0; r < 8; ++r) {
        const int row = n0 + r0 + r;
        if (row < NNODES) {
            ushort4 sv;
            sv.x = f2bf(acc[r][0]); sv.y = f2bf(acc[r][1]);
            sv.z = f2bf(acc[r][2]); sv.w = f2bf(acc[r][3]);
            *(ushort4*)(Pm + (size_t)row * HID + c4) = sv;
        }
    }
}

// ---------------- K2: fused edge pass — unnormalized softmax-weighted scatter
__global__ __launch_bounds__(256)
void edge_kernel(const int* __restrict__ adj,
                 const unsigned short* __restrict__ P,
                 float* __restrict__ outacc,
                 float* __restrict__ sumexp)
{
    const int tid  = threadIdx.x;
    const int wave = tid >> 6;
    const int lane = tid & 63;
    const int W    = blockIdx.x * 4 + wave;
    if (W * EPW >= NE) return;
    const int e0 = W * EPW;

    const unsigned short* Pq = P;
    const unsigned short* Pk = Pq + (size_t)NNODES * HID;
    const unsigned short* Pa = Pk + (size_t)NNODES * HID;
    const unsigned short* Pb = Pa + (size_t)NNODES * HID;
    const int j0 = lane * 2;         // this lane's 2 cols
    const int h  = lane >> 3;        // head of this lane's cols

    for (int chunk = 0; chunk < EPW; chunk += 8) {
        int tgts[8];
        uint32 qv[8], kv[8], av[8], bv[8];
        #pragma unroll
        for (int e = 0; e < 8; ++e) {
            const int eid = e0 + chunk + e;
            const int s  = adj[2 * eid];          // wave-uniform -> s_load
            const int tg = adj[2 * eid + 1];
            tgts[e] = tg;
            qv[e] = *(const uint32*)(Pq + (size_t)tg * HID + j0);
            kv[e] = *(const uint32*)(Pk + (size_t)s  * HID + j0);
            av[e] = *(const uint32*)(Pa + (size_t)s  * HID + j0);
            bv[e] = *(const uint32*)(Pb + (size_t)tg * HID + j0);
        }
        #pragma unroll
        for (int e = 0; e < 8; ++e) {
            float d = (bflo(qv[e]) * bflo(kv[e]) + bfhi(qv[e]) * bfhi(kv[e])) * 0.25f;
            d += __shfl_xor(d, 1);
            d += __shfl_xor(d, 2);
            d += __shfl_xor(d, 4);                 // all 8 lanes of head group hold s
            const float ex = __expf(d);
            const float m0 = fmaxf(bflo(av[e]) + bflo(bv[e]), 0.f);
            const float m1 = fmaxf(bfhi(av[e]) + bfhi(bv[e]), 0.f);
            float* o = outacc + (size_t)tgts[e] * HID + j0;
            unsafeAtomicAdd(o,     ex * m0);
            unsafeAtomicAdd(o + 1, ex * m1);
            if ((lane & 7) == 0)
                unsafeAtomicAdd(sumexp + (size_t)tgts[e] * 8 + h, ex);
        }
    }
}

// ---------------- K3: divide by sumexp (0 if node has no in-edges)
__global__ __launch_bounds__(256)
void finalize_kernel(float* __restrict__ out, const float* __restrict__ sumexp)
{
    const int gid = blockIdx.x * 256 + threadIdx.x;   // one float4 per thread
    if (gid >= NNODES * 32) return;
    const int node = gid >> 5;
    const int c4   = (gid & 31) * 4;                  // 4 cols, all in head c4>>4
    const float se = sumexp[(size_t)node * 8 + (c4 >> 4)];
    const float inv = se > 0.f ? 1.f / se : 0.f;
    float4 v = *(float4*)(out + (size_t)node * HID + c4);
    v.x *= inv; v.y *= inv; v.z *= inv; v.w *= inv;
    *(float4*)(out + (size_t)node * HID + c4) = v;
}

extern "C" void kernel_launch(void* const* d_in, const int* in_sizes, int n_in,
                              void* d_out, int out_size, void* d_ws, size_t ws_size,
                              hipStream_t stream)
{
    const float* x  = (const float*)d_in[0];
    const int* adjs[NT] = { (const int*)d_in[1], (const int*)d_in[2], (const int*)d_in[3] };
    const float* Wq = (const float*)d_in[4];
    const float* Wk = (const float*)d_in[5];
    const float* Wm = (const float*)d_in[6];
    const float* bm = (const float*)d_in[7];
    float* out = (float*)d_out;

    // ws: sumexp f32 [50000*8] (1.6 MB) | P bf16 4x[50000*128] (51.2 MB)
    float* sumexp = (float*)d_ws;
    unsigned short* P = (unsigned short*)((char*)d_ws + (size_t)NNODES * 8 * sizeof(float));

    hipMemsetAsync(out,    0, (size_t)NNODES * HID * sizeof(float), stream);
    hipMemsetAsync(sumexp, 0, (size_t)NNODES * 8 * sizeof(float), stream);

    const int pre_blk  = (NNODES + 63) / 64;            // 782
    const int edge_blk = (NE / EPW + 3) / 4;            // 3907 (15625 waves)
    for (int t = 0; t < NT; ++t) {
        precompute_kernel<<<dim3(pre_blk, 4), 256, 0, stream>>>(x, Wq, Wk, Wm, bm, P, t);
        edge_kernel<<<edge_blk, 256, 0, stream>>>(adjs[t], P, out, sumexp);
    }
    finalize_kernel<<<(NNODES * 32 + 255) / 256, 256, 0, stream>>>(out, sumexp);
}

// Round 3
// 470.572 us; speedup vs baseline: 4.3625x; 2.2099x over previous
//
#include <hip/hip_runtime.h>

#define HID 128
#define NE 250000
#define NT 3
#define NN 50000
#define NSEG (NT * NN)          // 150000 segments (type-major)
#define NB1 586                 // ceil(NSEG/256)

typedef unsigned int u32;
typedef unsigned short u16;
typedef __attribute__((ext_vector_type(8))) short short8;
typedef __attribute__((ext_vector_type(4))) float f32x4;

__device__ __forceinline__ u16 f2bf(float f) {
    u32 u = __float_as_uint(f);
    u += 0x7fffu + ((u >> 16) & 1u);      // RNE, inputs finite
    return (u16)(u >> 16);
}
__device__ __forceinline__ float bflo(u32 u) { return __uint_as_float(u << 16); }
__device__ __forceinline__ float bfhi(u32 u) { return __uint_as_float(u & 0xffff0000u); }

// ---- x (f32) -> Xbf (bf16), one float4 per thread
__global__ __launch_bounds__(256)
void xbf_kernel(const float* __restrict__ x, u16* __restrict__ Xbf)
{
    const int gid = blockIdx.x * 256 + threadIdx.x;
    if (gid >= NN * HID / 4) return;
    const float4 v = ((const float4*)x)[gid];
    ushort4 o;
    o.x = f2bf(v.x); o.y = f2bf(v.y); o.z = f2bf(v.z); o.w = f2bf(v.w);
    ((ushort4*)Xbf)[gid] = o;
}

// ---- W -> Wtb[t][m][n][k] bf16 (transposed so B-fragments are contiguous in k)
__global__ __launch_bounds__(256)
void wt_kernel(const float* __restrict__ Wq, const float* __restrict__ Wk,
               const float* __restrict__ Wm, u16* __restrict__ Wtb)
{
    const int gid = blockIdx.x * 256 + threadIdx.x;     // 12 * 16384
    const int mat = gid >> 14;
    const int i   = gid & 16383;                        // i = k*128 + n
    const int k   = i >> 7;
    const int n   = i & 127;
    const int t   = mat >> 2;
    const int m   = mat & 3;
    const float* src;
    if (m == 0)      src = Wq + (size_t)t * 16384;
    else if (m == 1) src = Wk + (size_t)t * 16384;
    else if (m == 2) src = Wm + (size_t)t * 32768;
    else             src = Wm + (size_t)t * 32768 + 16384;
    Wtb[(size_t)mat * 16384 + n * HID + k] = f2bf(src[i]);
}

// ---- CSR build: count / scan / scatter
__global__ __launch_bounds__(256)
void count_kernel(const int* __restrict__ a0, const int* __restrict__ a1,
                  const int* __restrict__ a2, u32* __restrict__ counts)
{
    const int gid = blockIdx.x * 256 + threadIdx.x;
    if (gid >= NT * NE) return;
    const int t = gid / NE, e = gid - t * NE;
    const int* adj = (t == 0) ? a0 : (t == 1) ? a1 : a2;
    atomicAdd(&counts[t * NN + adj[2 * e + 1]], 1u);
}

__global__ __launch_bounds__(256)
void scan1_kernel(const u32* __restrict__ counts, u32* __restrict__ bsum)
{
    __shared__ u32 s[256];
    const int tid = threadIdx.x;
    const int idx = blockIdx.x * 256 + tid;
    s[tid] = (idx < NSEG) ? counts[idx] : 0u;
    __syncthreads();
    for (int st = 128; st > 0; st >>= 1) {
        if (tid < st) s[tid] += s[tid + st];
        __syncthreads();
    }
    if (tid == 0) bsum[blockIdx.x] = s[0];
}

__global__ __launch_bounds__(1024)
void scan2_kernel(u32* __restrict__ bsum)        // exclusive scan of NB1 block sums
{
    __shared__ u32 s[1024];
    const int tid = threadIdx.x;
    const u32 v = (tid < NB1) ? bsum[tid] : 0u;
    s[tid] = v;
    __syncthreads();
    for (int st = 1; st < 1024; st <<= 1) {
        const u32 a = (tid >= st) ? s[tid - st] : 0u;
        __syncthreads();
        s[tid] += a;
        __syncthreads();
    }
    if (tid < NB1) bsum[tid] = s[tid] - v;       // exclusive
}

__global__ __launch_bounds__(256)
void scan3_kernel(const u32* __restrict__ counts, const u32* __restrict__ bsum,
                  u32* __restrict__ offsets, u32* __restrict__ cursors)
{
    __shared__ u32 s[256];
    const int tid = threadIdx.x;
    const int idx = blockIdx.x * 256 + tid;
    const u32 v = (idx < NSEG) ? counts[idx] : 0u;
    s[tid] = v;
    __syncthreads();
    for (int st = 1; st < 256; st <<= 1) {
        const u32 a = (tid >= st) ? s[tid - st] : 0u;
        __syncthreads();
        s[tid] += a;
        __syncthreads();
    }
    if (idx < NSEG) {
        const u32 off = bsum[blockIdx.x] + s[tid] - v;
        offsets[idx] = off;
        cursors[idx] = off;
    }
}

__global__ __launch_bounds__(256)
void scatter_kernel(const int* __restrict__ a0, const int* __restrict__ a1,
                    const int* __restrict__ a2, u32* __restrict__ cursors,
                    u32* __restrict__ edata)
{
    const int gid = blockIdx.x * 256 + threadIdx.x;
    if (gid >= NT * NE) return;
    const int t = gid / NE, e = gid - t * NE;
    const int* adj = (t == 0) ? a0 : (t == 1) ? a1 : a2;
    const int src = adj[2 * e];
    const int tgt = adj[2 * e + 1];
    const u32 pos = atomicAdd(&cursors[t * NN + tgt], 1u);
    edata[pos] = (u32)src;
}

// ---- MFMA precompute: P[m][row][col] bf16 = (Xbf @ W[t][m]) (+bias for m==3)
// wave: 32 rows (2 row-tiles of 16) x 128 cols (8 col-tiles of 16), K=128 in 4 steps
__global__ __launch_bounds__(256)
void gemm_kernel(const u16* __restrict__ Xbf, const u16* __restrict__ Wtb,
                 const float* __restrict__ bm, u16* __restrict__ P, int t)
{
    const int wave = threadIdx.x >> 6, lane = threadIdx.x & 63;
    const int m    = blockIdx.y;
    const int lm   = lane & 15, quad = lane >> 4;
    const int r0   = blockIdx.x * 128 + wave * 32;
    const u16* Wt  = Wtb + (size_t)(t * 4 + m) * 16384;

    int ar[2];
    ar[0] = min(r0 + lm,      NN - 1);      // clamp: junk rows computed, store guarded
    ar[1] = min(r0 + 16 + lm, NN - 1);

    f32x4 acc[2][8];
    #pragma unroll
    for (int rt = 0; rt < 2; ++rt)
        #pragma unroll
        for (int ct = 0; ct < 8; ++ct)
            acc[rt][ct] = (f32x4){0.f, 0.f, 0.f, 0.f};

    for (int k0 = 0; k0 < HID; k0 += 32) {
        short8 A[2], B[8];
        // A[m=lane&15][k=quad*8+j] : contiguous 8 bf16 from row-major Xbf
        A[0] = *(const short8*)(Xbf + (size_t)ar[0] * HID + k0 + quad * 8);
        A[1] = *(const short8*)(Xbf + (size_t)ar[1] * HID + k0 + quad * 8);
        // B[k=quad*8+j][n=lane&15] : contiguous 8 bf16 from transposed Wtb[n][k]
        #pragma unroll
        for (int ct = 0; ct < 8; ++ct)
            B[ct] = *(const short8*)(Wt + (size_t)(ct * 16 + lm) * HID + k0 + quad * 8);
        #pragma unroll
        for (int rt = 0; rt < 2; ++rt)
            #pragma unroll
            for (int ct = 0; ct < 8; ++ct)
                acc[rt][ct] = __builtin_amdgcn_mfma_f32_16x16x32_bf16(
                    A[rt], B[ct], acc[rt][ct], 0, 0, 0);
    }

    // C/D: col = lane&15, row = quad*4 + reg  (m89/m91-verified)
    u16* Pm = P + (size_t)m * NN * HID;
    #pragma unroll
    for (int ct = 0; ct < 8; ++ct) {
        const int n = ct * 16 + lm;
        const float bias = (m == 3) ? bm[t * HID + n] : 0.f;
        #pragma unroll
        for (int rt = 0; rt < 2; ++rt) {
            const int rbase = r0 + rt * 16 + quad * 4;
            #pragma unroll
            for (int reg = 0; reg < 4; ++reg) {
                const int row = rbase + reg;
                if (row < NN)
                    Pm[(size_t)row * HID + n] = f2bf(acc[rt][ct][reg] + bias);
            }
        }
    }
}

// ---- gather: one wave per node; register accumulate; single float2 RMW per node
__global__ __launch_bounds__(256)
void gather_kernel(const u16* __restrict__ P, const u32* __restrict__ offsets,
                   const u32* __restrict__ counts, const u32* __restrict__ edata,
                   float* __restrict__ out, float* __restrict__ sumexp,
                   int t, int isfinal)
{
    const int wave = threadIdx.x >> 6, lane = threadIdx.x & 63;
    const int node = blockIdx.x * 4 + wave;
    if (node >= NN) return;
    const int seg   = t * NN + node;
    const u32 start = offsets[seg];
    const int deg   = (int)counts[seg];
    const int j0 = lane * 2, h = lane >> 3;

    const u16* Pq = P;
    const u16* Pk = P + (size_t)NN * HID;
    const u16* Pa = P + (size_t)2 * NN * HID;
    const u16* Pb = P + (size_t)3 * NN * HID;

    const u32 qv = *(const u32*)(Pq + (size_t)node * HID + j0);
    const u32 bv = *(const u32*)(Pb + (size_t)node * HID + j0);
    const float q0 = bflo(qv) * 0.25f, q1 = bfhi(qv) * 0.25f;  // fold 1/sqrt(16)
    const float b0 = bflo(bv), b1 = bfhi(bv);

    float acc0 = 0.f, acc1 = 0.f, den = 0.f;
    int e = 0;
    for (; e + 4 <= deg; e += 4) {
        u32 kv[4], av[4];
        #pragma unroll
        for (int u = 0; u < 4; ++u) {
            const int src = __builtin_amdgcn_readfirstlane((int)edata[start + e + u]);
            kv[u] = *(const u32*)(Pk + (size_t)src * HID + j0);
            av[u] = *(const u32*)(Pa + (size_t)src * HID + j0);
        }
        #pragma unroll
        for (int u = 0; u < 4; ++u) {
            float d = q0 * bflo(kv[u]) + q1 * bfhi(kv[u]);
            d += __shfl_xor(d, 1);
            d += __shfl_xor(d, 2);
            d += __shfl_xor(d, 4);
            const float ex = __expf(d);
            acc0 += ex * fmaxf(bflo(av[u]) + b0, 0.f);
            acc1 += ex * fmaxf(bfhi(av[u]) + b1, 0.f);
            den  += ex;
        }
    }
    for (; e < deg; ++e) {
        const int src = __builtin_amdgcn_readfirstlane((int)edata[start + e]);
        const u32 kv = *(const u32*)(Pk + (size_t)src * HID + j0);
        const u32 av = *(const u32*)(Pa + (size_t)src * HID + j0);
        float d = q0 * bflo(kv) + q1 * bfhi(kv);
        d += __shfl_xor(d, 1);
        d += __shfl_xor(d, 2);
        d += __shfl_xor(d, 4);
        const float ex = __expf(d);
        acc0 += ex * fmaxf(bflo(av) + b0, 0.f);
        acc1 += ex * fmaxf(bfhi(av) + b1, 0.f);
        den  += ex;
    }

    float* op = out + (size_t)node * HID + j0;
    if (isfinal) {
        const float tot = sumexp[(size_t)node * 8 + h] + den;  // den uniform in head group
        const float inv = tot > 0.f ? 1.f / tot : 0.f;
        float2 o = *(float2*)op;
        o.x = (o.x + acc0) * inv;
        o.y = (o.y + acc1) * inv;
        *(float2*)op = o;
    } else {
        if (deg == 0) return;
        float2 o = *(float2*)op;
        o.x += acc0; o.y += acc1;
        *(float2*)op = o;                       // node owned by this wave: no atomics
        if ((lane & 7) == 0) sumexp[(size_t)node * 8 + h] += den;
    }
}

extern "C" void kernel_launch(void* const* d_in, const int* in_sizes, int n_in,
                              void* d_out, int out_size, void* d_ws, size_t ws_size,
                              hipStream_t stream)
{
    const float* x  = (const float*)d_in[0];
    const int* a0   = (const int*)d_in[1];
    const int* a1   = (const int*)d_in[2];
    const int* a2   = (const int*)d_in[3];
    const float* Wq = (const float*)d_in[4];
    const float* Wk = (const float*)d_in[5];
    const float* Wm = (const float*)d_in[6];
    const float* bm = (const float*)d_in[7];
    float* out = (float*)d_out;

    // ws layout (bytes), ~70.8 MB total
    char* ws = (char*)d_ws;
    u16* P       = (u16*)(ws + 0);           // 4 planes x 50000x128 bf16 = 51.2 MB (per type)
    u16* Xbf     = (u16*)(ws + 51200000);    // 12.8 MB
    u16* Wtb     = (u16*)(ws + 64000000);    // 12 x 32 KB transposed bf16
    u32* counts  = (u32*)(ws + 64393216);    // 150000
    u32* offsets = (u32*)(ws + 64993216);    // 150000
    u32* cursors = (u32*)(ws + 65593216);    // 150000
    u32* bsum    = (u32*)(ws + 66193216);    // 1024
    u32* edata   = (u32*)(ws + 66197312);    // 750000
    float* sumexp= (float*)(ws + 69197312);  // 50000x8

    hipMemsetAsync(out,    0, (size_t)NN * HID * sizeof(float), stream);
    hipMemsetAsync(sumexp, 0, (size_t)NN * 8 * sizeof(float), stream);
    hipMemsetAsync(counts, 0, (size_t)NSEG * sizeof(u32), stream);

    xbf_kernel<<<(NN * HID / 4 + 255) / 256, 256, 0, stream>>>(x, Xbf);
    wt_kernel<<<(12 * 16384) / 256, 256, 0, stream>>>(Wq, Wk, Wm, Wtb);
    count_kernel<<<(NT * NE + 255) / 256, 256, 0, stream>>>(a0, a1, a2, counts);
    scan1_kernel<<<NB1, 256, 0, stream>>>(counts, bsum);
    scan2_kernel<<<1, 1024, 0, stream>>>(bsum);
    scan3_kernel<<<NB1, 256, 0, stream>>>(counts, bsum, offsets, cursors);
    scatter_kernel<<<(NT * NE + 255) / 256, 256, 0, stream>>>(a0, a1, a2, cursors, edata);

    const int gx = (NN + 127) / 128;         // 391
    for (int t = 0; t < NT; ++t) {
        gemm_kernel<<<dim3(gx, 4), 256, 0, stream>>>(Xbf, Wtb, bm, P, t);
        gather_kernel<<<(NN + 3) / 4, 256, 0, stream>>>(P, offsets, counts, edata,
                                                        out, sumexp, t, t == 2 ? 1 : 0);
    }
}

// Round 4
// 330.582 us; speedup vs baseline: 6.2098x; 1.4235x over previous
//
#include <hip/hip_runtime.h>

#define HID 128
#define NE 250000
#define NT 3
#define NN 50000
#define NSEG (NT * NN)          // 150000 segments (type-major)
#define NB1 586                 // ceil(NSEG/256)
#define BPAD 136                // LDS B row stride in halves (272B: 16B-aligned, 2-way banks)

typedef unsigned int u32;
typedef unsigned short u16;
typedef __attribute__((ext_vector_type(8))) short short8;
typedef __attribute__((ext_vector_type(4))) float f32x4;

__device__ __forceinline__ u16 f2bf(float f) {
    u32 u = __float_as_uint(f);
    u += 0x7fffu + ((u >> 16) & 1u);      // RNE, inputs finite
    return (u16)(u >> 16);
}
__device__ __forceinline__ float bflo(u32 u) { return __uint_as_float(u << 16); }
__device__ __forceinline__ float bfhi(u32 u) { return __uint_as_float(u & 0xffff0000u); }

// ---- prep: xbf convert | W transpose+convert | CSR degree count, one dispatch
__global__ __launch_bounds__(256)
void prep_kernel(const float* __restrict__ x,
                 const float* __restrict__ Wq, const float* __restrict__ Wk,
                 const float* __restrict__ Wm,
                 u16* __restrict__ Xbf, u16* __restrict__ Wtb,
                 const int* __restrict__ a0, const int* __restrict__ a1,
                 const int* __restrict__ a2, u32* __restrict__ counts)
{
    const int b = blockIdx.x, tid = threadIdx.x;
    if (b < 6250) {                       // x -> bf16, 1,600,000 float4 exactly
        const int gid = b * 256 + tid;
        const float4 v = ((const float4*)x)[gid];
        ushort4 o;
        o.x = f2bf(v.x); o.y = f2bf(v.y); o.z = f2bf(v.z); o.w = f2bf(v.w);
        ((ushort4*)Xbf)[gid] = o;
    } else if (b < 7018) {                // W -> Wtb[mat][n][k] bf16, 196,608 exactly
        const int gid = (b - 6250) * 256 + tid;
        const int mat = gid >> 14;
        const int i   = gid & 16383;      // i = k*128 + n
        const int k   = i >> 7;
        const int n   = i & 127;
        const int t   = mat >> 2;
        const int m   = mat & 3;
        const float* src;
        if (m == 0)      src = Wq + (size_t)t * 16384;
        else if (m == 1) src = Wk + (size_t)t * 16384;
        else if (m == 2) src = Wm + (size_t)t * 32768;
        else             src = Wm + (size_t)t * 32768 + 16384;
        Wtb[(size_t)mat * 16384 + n * HID + k] = f2bf(src[i]);
    } else {                              // degree count
        const int gid = (b - 7018) * 256 + tid;
        if (gid >= NT * NE) return;
        const int t = gid / NE, e = gid - t * NE;
        const int* adj = (t == 0) ? a0 : (t == 1) ? a1 : a2;
        atomicAdd(&counts[t * NN + adj[2 * e + 1]], 1u);
    }
}

// ---- CSR scan / scatter (unchanged from R3)
__global__ __launch_bounds__(256)
void scan1_kernel(const u32* __restrict__ counts, u32* __restrict__ bsum)
{
    __shared__ u32 s[256];
    const int tid = threadIdx.x;
    const int idx = blockIdx.x * 256 + tid;
    s[tid] = (idx < NSEG) ? counts[idx] : 0u;
    __syncthreads();
    for (int st = 128; st > 0; st >>= 1) {
        if (tid < st) s[tid] += s[tid + st];
        __syncthreads();
    }
    if (tid == 0) bsum[blockIdx.x] = s[0];
}

__global__ __launch_bounds__(1024)
void scan2_kernel(u32* __restrict__ bsum)
{
    __shared__ u32 s[1024];
    const int tid = threadIdx.x;
    const u32 v = (tid < NB1) ? bsum[tid] : 0u;
    s[tid] = v;
    __syncthreads();
    for (int st = 1; st < 1024; st <<= 1) {
        const u32 a = (tid >= st) ? s[tid - st] : 0u;
        __syncthreads();
        s[tid] += a;
        __syncthreads();
    }
    if (tid < NB1) bsum[tid] = s[tid] - v;
}

__global__ __launch_bounds__(256)
void scan3_kernel(const u32* __restrict__ counts, const u32* __restrict__ bsum,
                  u32* __restrict__ offsets, u32* __restrict__ cursors)
{
    __shared__ u32 s[256];
    const int tid = threadIdx.x;
    const int idx = blockIdx.x * 256 + tid;
    const u32 v = (idx < NSEG) ? counts[idx] : 0u;
    s[tid] = v;
    __syncthreads();
    for (int st = 1; st < 256; st <<= 1) {
        const u32 a = (tid >= st) ? s[tid - st] : 0u;
        __syncthreads();
        s[tid] += a;
        __syncthreads();
    }
    if (idx < NSEG) {
        const u32 off = bsum[blockIdx.x] + s[tid] - v;
        offsets[idx] = off;
        cursors[idx] = off;
    }
}

__global__ __launch_bounds__(256)
void scatter_kernel(const int* __restrict__ a0, const int* __restrict__ a1,
                    const int* __restrict__ a2, u32* __restrict__ cursors,
                    u32* __restrict__ edata)
{
    const int gid = blockIdx.x * 256 + threadIdx.x;
    if (gid >= NT * NE) return;
    const int t = gid / NE, e = gid - t * NE;
    const int* adj = (t == 0) ? a0 : (t == 1) ? a1 : a2;
    const int src = adj[2 * e];
    const int tgt = adj[2 * e + 1];
    const u32 pos = atomicAdd(&cursors[t * NN + tgt], 1u);
    edata[pos] = (u32)src;
}

// ---- MFMA gemm: plane(by) = Xbf @ W[mat] (+bias if m==3); B staged in LDS
// grid (391, nmat); mat = tbase*4 + by. Wave: 32 rows x 128 cols, K=128.
__global__ __launch_bounds__(256)
void gemm_kernel(const u16* __restrict__ Xbf, const u16* __restrict__ Wtb,
                 const float* __restrict__ bm, u16* __restrict__ P, int tbase)
{
    __shared__ u16 Bs[128 * BPAD];        // 34,816 B
    const int tid = threadIdx.x;
    const int by  = blockIdx.y;
    const int mat = tbase * 4 + by;
    const int t   = mat >> 2, m = mat & 3;
    const u16* Wt = Wtb + (size_t)mat * 16384;

    // stage B tile (128 n-rows x 128 k, bf16) into padded LDS: 2048 x 16B
    for (int c = tid; c < 2048; c += 256) {
        const int r = c >> 4, s = (c & 15) * 8;
        *(short8*)&Bs[r * BPAD + s] = *(const short8*)(Wt + r * HID + s);
    }
    __syncthreads();

    const int wave = tid >> 6, lane = tid & 63;
    const int lm = lane & 15, quad = lane >> 4;
    const int r0 = blockIdx.x * 128 + wave * 32;
    const int ar0 = min(r0 + lm,      NN - 1);   // clamp; stores guarded
    const int ar1 = min(r0 + 16 + lm, NN - 1);

    f32x4 acc[2][8];
    #pragma unroll
    for (int rt = 0; rt < 2; ++rt)
        #pragma unroll
        for (int ct = 0; ct < 8; ++ct)
            acc[rt][ct] = (f32x4){0.f, 0.f, 0.f, 0.f};

    for (int k0 = 0; k0 < HID; k0 += 32) {
        // A[m=lane&15][k=quad*8+j] — m89/m91-verified
        const short8 A0 = *(const short8*)(Xbf + (size_t)ar0 * HID + k0 + quad * 8);
        const short8 A1 = *(const short8*)(Xbf + (size_t)ar1 * HID + k0 + quad * 8);
        #pragma unroll
        for (int ct = 0; ct < 8; ++ct) {
            const short8 B = *(const short8*)&Bs[(ct * 16 + lm) * BPAD + k0 + quad * 8];
            acc[0][ct] = __builtin_amdgcn_mfma_f32_16x16x32_bf16(A0, B, acc[0][ct], 0, 0, 0);
            acc[1][ct] = __builtin_amdgcn_mfma_f32_16x16x32_bf16(A1, B, acc[1][ct], 0, 0, 0);
        }
    }

    // C/D: col = lane&15, row = quad*4 + reg (m89/m91-verified)
    u16* Pm = P + (size_t)by * NN * HID;
    #pragma unroll
    for (int ct = 0; ct < 8; ++ct) {
        const int n = ct * 16 + lm;
        const float bias = (m == 3) ? bm[t * HID + n] : 0.f;
        #pragma unroll
        for (int rt = 0; rt < 2; ++rt) {
            const int rbase = r0 + rt * 16 + quad * 4;
            #pragma unroll
            for (int reg = 0; reg < 4; ++reg) {
                const int row = rbase + reg;
                if (row < NN)
                    Pm[(size_t)row * HID + n] = f2bf(acc[rt][ct][reg] + bias);
            }
        }
    }
}

// ---- gather: one wave per node; loops ntypes types, acc/den in registers.
// mode: 0 = accumulate (RMW out + sumexp), 1 = final using sumexp, 2 = final pure
__global__ __launch_bounds__(256)
void gather_kernel(const u16* __restrict__ P, const u32* __restrict__ offsets,
                   const u32* __restrict__ counts, const u32* __restrict__ edata,
                   float* __restrict__ out, float* __restrict__ sumexp,
                   int tbase, int ntypes, int mode)
{
    const int wave = threadIdx.x >> 6, lane = threadIdx.x & 63;
    const int node = blockIdx.x * 4 + wave;
    if (node >= NN) return;
    const int j0 = lane * 2, h = lane >> 3;

    float acc0 = 0.f, acc1 = 0.f, den = 0.f;
    int degtot = 0;

    for (int tt = 0; tt < ntypes; ++tt) {
        const u16* Pt = P + (size_t)tt * 4 * NN * HID;
        const u16* Pq = Pt;
        const u16* Pk = Pt + (size_t)NN * HID;
        const u16* Pa = Pt + (size_t)2 * NN * HID;
        const u16* Pb = Pt + (size_t)3 * NN * HID;
        const int seg   = (tbase + tt) * NN + node;
        const u32 start = offsets[seg];
        const int deg   = (int)counts[seg];
        degtot += deg;
        if (deg == 0) continue;

        const u32 qv  = *(const u32*)(Pq + (size_t)node * HID + j0);
        const u32 bv2 = *(const u32*)(Pb + (size_t)node * HID + j0);
        const float q0 = bflo(qv) * 0.25f, q1 = bfhi(qv) * 0.25f;  // fold PHD^-0.5
        const float b0 = bflo(bv2), b1 = bfhi(bv2);

        int e = 0;
        for (; e + 4 <= deg; e += 4) {
            u32 kv[4], av[4];
            #pragma unroll
            for (int u = 0; u < 4; ++u) {
                const int src = __builtin_amdgcn_readfirstlane((int)edata[start + e + u]);
                kv[u] = *(const u32*)(Pk + (size_t)src * HID + j0);
                av[u] = *(const u32*)(Pa + (size_t)src * HID + j0);
            }
            #pragma unroll
            for (int u = 0; u < 4; ++u) {
                float d = q0 * bflo(kv[u]) + q1 * bfhi(kv[u]);
                d += __shfl_xor(d, 1);
                d += __shfl_xor(d, 2);
                d += __shfl_xor(d, 4);
                const float ex = __expf(d);
                acc0 += ex * fmaxf(bflo(av[u]) + b0, 0.f);
                acc1 += ex * fmaxf(bfhi(av[u]) + b1, 0.f);
                den  += ex;
            }
        }
        for (; e < deg; ++e) {
            const int src = __builtin_amdgcn_readfirstlane((int)edata[start + e]);
            const u32 kv = *(const u32*)(Pk + (size_t)src * HID + j0);
            const u32 av = *(const u32*)(Pa + (size_t)src * HID + j0);
            float d = q0 * bflo(kv) + q1 * bfhi(kv);
            d += __shfl_xor(d, 1);
            d += __shfl_xor(d, 2);
            d += __shfl_xor(d, 4);
            const float ex = __expf(d);
            acc0 += ex * fmaxf(bflo(av) + b0, 0.f);
            acc1 += ex * fmaxf(bfhi(av) + b1, 0.f);
            den  += ex;
        }
    }

    float* op = out + (size_t)node * HID + j0;
    if (mode == 2) {                       // fused: softmax over all 3 types in-register
        const float inv = den > 0.f ? 1.f / den : 0.f;
        float2 o;
        o.x = acc0 * inv;
        o.y = acc1 * inv;
        *(float2*)op = o;
    } else if (mode == 1) {
        const float tot = sumexp[(size_t)node * 8 + h] + den;
        const float inv = tot > 0.f ? 1.f / tot : 0.f;
        float2 o = *(float2*)op;
        o.x = (o.x + acc0) * inv;
        o.y = (o.y + acc1) * inv;
        *(float2*)op = o;
    } else {
        if (degtot == 0) return;
        float2 o = *(float2*)op;
        o.x += acc0; o.y += acc1;
        *(float2*)op = o;
        if ((lane & 7) == 0) sumexp[(size_t)node * 8 + h] += den;
    }
}

extern "C" void kernel_launch(void* const* d_in, const int* in_sizes, int n_in,
                              void* d_out, int out_size, void* d_ws, size_t ws_size,
                              hipStream_t stream)
{
    const float* x  = (const float*)d_in[0];
    const int* a0   = (const int*)d_in[1];
    const int* a1   = (const int*)d_in[2];
    const int* a2   = (const int*)d_in[3];
    const float* Wq = (const float*)d_in[4];
    const float* Wk = (const float*)d_in[5];
    const float* Wm = (const float*)d_in[6];
    const float* bm = (const float*)d_in[7];
    float* out = (float*)d_out;

    // ws layout; fused path needs 12 P planes (173.2 MB), fallback 4 (70.8 MB).
    const size_t planeB = (size_t)NN * HID * sizeof(u16);    // 12.8 MB
    const size_t fixedB = 12800000 + 393216 + 3 * 600000 + 4096 + 3000000 + 1600000;
    const int fused = (ws_size >= 12 * planeB + fixedB) ? 1 : 0;
    const int npl = fused ? 12 : 4;

    char* p = (char*)d_ws;
    u16* P        = (u16*)p;            p += (size_t)npl * planeB;
    u16* Xbf      = (u16*)p;            p += 12800000;
    u16* Wtb      = (u16*)p;            p += 393216;
    u32* counts   = (u32*)p;            p += 600000;
    u32* offsets  = (u32*)p;            p += 600000;
    u32* cursors  = (u32*)p;            p += 600000;
    u32* bsum     = (u32*)p;            p += 4096;
    u32* edata    = (u32*)p;            p += 3000000;
    float* sumexp = (float*)p;

    hipMemsetAsync(counts, 0, (size_t)NSEG * sizeof(u32), stream);
    if (!fused) {
        hipMemsetAsync(out,    0, (size_t)NN * HID * sizeof(float), stream);
        hipMemsetAsync(sumexp, 0, (size_t)NN * 8 * sizeof(float), stream);
    }

    prep_kernel<<<7018 + (NT * NE + 255) / 256, 256, 0, stream>>>(
        x, Wq, Wk, Wm, Xbf, Wtb, a0, a1, a2, counts);
    scan1_kernel<<<NB1, 256, 0, stream>>>(counts, bsum);
    scan2_kernel<<<1, 1024, 0, stream>>>(bsum);
    scan3_kernel<<<NB1, 256, 0, stream>>>(counts, bsum, offsets, cursors);
    scatter_kernel<<<(NT * NE + 255) / 256, 256, 0, stream>>>(a0, a1, a2, cursors, edata);

    const int gx = (NN + 127) / 128;    // 391
    const int gb = (NN + 3) / 4;        // 12500
    if (fused) {
        gemm_kernel<<<dim3(gx, 12), 256, 0, stream>>>(Xbf, Wtb, bm, P, 0);
        gather_kernel<<<gb, 256, 0, stream>>>(P, offsets, counts, edata,
                                              out, sumexp, 0, 3, 2);
    } else {
        for (int t = 0; t < NT; ++t) {
            gemm_kernel<<<dim3(gx, 4), 256, 0, stream>>>(Xbf, Wtb, bm, P, t);
            gather_kernel<<<gb, 256, 0, stream>>>(P, offsets, counts, edata,
                                                  out, sumexp, t, 1, t == 2 ? 1 : 0);
        }
    }
}

// Round 5
// 312.030 us; speedup vs baseline: 6.5791x; 1.0595x over previous
//
#include <hip/hip_runtime.h>

#define HID 128
#define NE 250000
#define NT 3
#define NN 50000
#define NSEG (NT * NN)          // 150000 segments (type-major)
#define NB1 586                 // ceil(NSEG/256)
#define BPAD 136                // LDS W row stride in halves (272B: 16B-aligned, 2-way banks)
#define PLANE (NN * 256)        // u16 elems per combined plane (512 B rows)

typedef unsigned int u32;
typedef unsigned short u16;
typedef __attribute__((ext_vector_type(8))) short short8;
typedef __attribute__((ext_vector_type(4))) float f32x4;

__device__ __forceinline__ u16 f2bf(float f) {
    u32 u = __float_as_uint(f);
    u += 0x7fffu + ((u >> 16) & 1u);      // RNE, inputs finite
    return (u16)(u >> 16);
}
__device__ __forceinline__ float bflo(u32 u) { return __uint_as_float(u << 16); }
__device__ __forceinline__ float bfhi(u32 u) { return __uint_as_float(u & 0xffff0000u); }

// ---- prep: xbf convert | W transpose+convert | CSR degree count, one dispatch
__global__ __launch_bounds__(256)
void prep_kernel(const float* __restrict__ x,
                 const float* __restrict__ Wq, const float* __restrict__ Wk,
                 const float* __restrict__ Wm,
                 u16* __restrict__ Xbf, u16* __restrict__ Wtb,
                 const int* __restrict__ a0, const int* __restrict__ a1,
                 const int* __restrict__ a2, u32* __restrict__ counts)
{
    const int b = blockIdx.x, tid = threadIdx.x;
    if (b < 6250) {                       // x -> bf16, 1,600,000 float4 exactly
        const int gid = b * 256 + tid;
        const float4 v = ((const float4*)x)[gid];
        ushort4 o;
        o.x = f2bf(v.x); o.y = f2bf(v.y); o.z = f2bf(v.z); o.w = f2bf(v.w);
        ((ushort4*)Xbf)[gid] = o;
    } else if (b < 7018) {                // W -> Wtb[mat][n][k] bf16, 196,608 exactly
        const int gid = (b - 6250) * 256 + tid;
        const int mat = gid >> 14;
        const int i   = gid & 16383;      // i = k*128 + n
        const int k   = i >> 7;
        const int n   = i & 127;
        const int t   = mat >> 2;
        const int m   = mat & 3;
        const float* src;
        if (m == 0)      src = Wq + (size_t)t * 16384;
        else if (m == 1) src = Wk + (size_t)t * 16384;
        else if (m == 2) src = Wm + (size_t)t * 32768;
        else             src = Wm + (size_t)t * 32768 + 16384;
        Wtb[(size_t)mat * 16384 + n * HID + k] = f2bf(src[i]);
    } else {                              // degree count
        const int gid = (b - 7018) * 256 + tid;
        if (gid >= NT * NE) return;
        const int t = gid / NE, e = gid - t * NE;
        const int* adj = (t == 0) ? a0 : (t == 1) ? a1 : a2;
        atomicAdd(&counts[t * NN + adj[2 * e + 1]], 1u);
    }
}

// ---- CSR scan / scatter
__global__ __launch_bounds__(256)
void scan1_kernel(const u32* __restrict__ counts, u32* __restrict__ bsum)
{
    __shared__ u32 s[256];
    const int tid = threadIdx.x;
    const int idx = blockIdx.x * 256 + tid;
    s[tid] = (idx < NSEG) ? counts[idx] : 0u;
    __syncthreads();
    for (int st = 128; st > 0; st >>= 1) {
        if (tid < st) s[tid] += s[tid + st];
        __syncthreads();
    }
    if (tid == 0) bsum[blockIdx.x] = s[0];
}

__global__ __launch_bounds__(1024)
void scan2_kernel(u32* __restrict__ bsum)
{
    __shared__ u32 s[1024];
    const int tid = threadIdx.x;
    const u32 v = (tid < NB1) ? bsum[tid] : 0u;
    s[tid] = v;
    __syncthreads();
    for (int st = 1; st < 1024; st <<= 1) {
        const u32 a = (tid >= st) ? s[tid - st] : 0u;
        __syncthreads();
        s[tid] += a;
        __syncthreads();
    }
    if (tid < NB1) bsum[tid] = s[tid] - v;
}

__global__ __launch_bounds__(256)
void scan3_kernel(const u32* __restrict__ counts, const u32* __restrict__ bsum,
                  u32* __restrict__ offsets, u32* __restrict__ cursors)
{
    __shared__ u32 s[256];
    const int tid = threadIdx.x;
    const int idx = blockIdx.x * 256 + tid;
    const u32 v = (idx < NSEG) ? counts[idx] : 0u;
    s[tid] = v;
    __syncthreads();
    for (int st = 1; st < 256; st <<= 1) {
        const u32 a = (tid >= st) ? s[tid - st] : 0u;
        __syncthreads();
        s[tid] += a;
        __syncthreads();
    }
    if (idx < NSEG) {
        const u32 off = bsum[blockIdx.x] + s[tid] - v;
        offsets[idx] = off;
        cursors[idx] = off;
    }
}

__global__ __launch_bounds__(256)
void scatter_kernel(const int* __restrict__ a0, const int* __restrict__ a1,
                    const int* __restrict__ a2, u32* __restrict__ cursors,
                    u32* __restrict__ edata)
{
    const int gid = blockIdx.x * 256 + threadIdx.x;
    if (gid >= NT * NE) return;
    const int t = gid / NE, e = gid - t * NE;
    const int* adj = (t == 0) ? a0 : (t == 1) ? a1 : a2;
    const int src = adj[2 * e];
    const int tgt = adj[2 * e + 1];
    const u32 pos = atomicAdd(&cursors[t * NN + tgt], 1u);
    edata[pos] = (u32)src;
}

// ---- MFMA gemm, transposed orientation: D = W^T (A) x X^T (B)
// C/D: n=lane&15 -> node, row=quad*4+reg -> outcol => lane holds 4 consecutive
// outcols of ONE node => 8 B coalesced-chunk stores (no repack needed).
// Planes: m=1(k)->KA half0, m=2(a)->KA half1, m=0(q)->QB half0, m=3(b)->QB half1.
__global__ __launch_bounds__(256)
void gemm_kernel(const u16* __restrict__ Xbf, const u16* __restrict__ Wtb,
                 const float* __restrict__ bm, u16* __restrict__ P,
                 int tbase, int fusedF)
{
    __shared__ u16 Ws[128 * BPAD];        // 34,816 B
    const int tid = threadIdx.x;
    const int by  = blockIdx.y;
    const int mat = tbase * 4 + by;
    const int t   = mat >> 2, m = mat & 3;
    const u16* Wt = Wtb + (size_t)mat * 16384;

    for (int c = tid; c < 2048; c += 256) {
        const int r = c >> 4, s = (c & 15) * 8;
        *(short8*)&Ws[r * BPAD + s] = *(const short8*)(Wt + r * HID + s);
    }
    __syncthreads();

    const int wave = tid >> 6, lane = tid & 63;
    const int lm = lane & 15, quad = lane >> 4;
    const int r0 = blockIdx.x * 128 + wave * 32;
    const int ar0 = min(r0 + lm,      NN - 1);   // clamp; stores guarded
    const int ar1 = min(r0 + 16 + lm, NN - 1);

    f32x4 acc[8][2];
    #pragma unroll
    for (int ct = 0; ct < 8; ++ct) {
        acc[ct][0] = (f32x4){0.f, 0.f, 0.f, 0.f};
        acc[ct][1] = (f32x4){0.f, 0.f, 0.f, 0.f};
    }

    for (int k0 = 0; k0 < HID; k0 += 32) {
        // B-frag (X^T): n=node=lane&15, k=quad*8+j -> contiguous in Xbf[node]
        const short8 X0 = *(const short8*)(Xbf + (size_t)ar0 * HID + k0 + quad * 8);
        const short8 X1 = *(const short8*)(Xbf + (size_t)ar1 * HID + k0 + quad * 8);
        #pragma unroll
        for (int ct = 0; ct < 8; ++ct) {
            // A-frag (W^T): m=outcol=lane&15, k=quad*8+j -> contiguous in Wtb[n][k]
            const short8 Wf = *(const short8*)&Ws[(ct * 16 + lm) * BPAD + k0 + quad * 8];
            acc[ct][0] = __builtin_amdgcn_mfma_f32_16x16x32_bf16(Wf, X0, acc[ct][0], 0, 0, 0);
            acc[ct][1] = __builtin_amdgcn_mfma_f32_16x16x32_bf16(Wf, X1, acc[ct][1], 0, 0, 0);
        }
    }

    const int half = (m == 2 || m == 3) ? 128 : 0;                 // a,b -> upper half
    const int pidx = (m == 1 || m == 2) ? (fusedF ? t : 0)         // KA plane
                                        : (fusedF ? (3 + t) : 1);  // QB plane
    u16* Pd = P + (size_t)pidx * PLANE + half;
    const int ocb = quad * 4;
    #pragma unroll
    for (int ct = 0; ct < 8; ++ct) {
        const int oc = ct * 16 + ocb;                // this lane's 4 outcols
        float b0 = 0.f, b1 = 0.f, b2 = 0.f, b3 = 0.f;
        if (m == 3) {
            const float4 bv = *(const float4*)(bm + t * HID + oc);
            b0 = bv.x; b1 = bv.y; b2 = bv.z; b3 = bv.w;
        }
        #pragma unroll
        for (int nt = 0; nt < 2; ++nt) {
            const int node = r0 + nt * 16 + lm;
            if (node < NN) {
                uint2 pk;
                pk.x = (u32)f2bf(acc[ct][nt][0] + b0) | ((u32)f2bf(acc[ct][nt][1] + b1) << 16);
                pk.y = (u32)f2bf(acc[ct][nt][2] + b2) | ((u32)f2bf(acc[ct][nt][3] + b3) << 16);
                *(uint2*)(Pd + (size_t)node * 256 + oc) = pk;
            }
        }
    }
}

// ---- gather: one wave per node; loops ntypes types, acc/den in registers.
// mode: 0 = accumulate (RMW out + sumexp), 1 = final using sumexp, 2 = final pure
__global__ __launch_bounds__(256)
void gather_kernel(const u16* __restrict__ P, const u32* __restrict__ offsets,
                   const u32* __restrict__ counts, const u32* __restrict__ edata,
                   float* __restrict__ out, float* __restrict__ sumexp,
                   int tbase, int ntypes, int mode, int fusedF)
{
    const int wave = threadIdx.x >> 6, lane = threadIdx.x & 63;
    const int node = blockIdx.x * 4 + wave;
    if (node >= NN) return;
    const int j0 = lane * 2, h = lane >> 3;

    float acc0 = 0.f, acc1 = 0.f, den = 0.f;
    int degtot = 0;

    for (int tt = 0; tt < ntypes; ++tt) {
        const u16* KA = P + (size_t)(fusedF ? tt : 0) * PLANE;
        const u16* QB = P + (size_t)(fusedF ? (3 + tt) : 1) * PLANE;
        const int seg   = (tbase + tt) * NN + node;
        const u32 start = offsets[seg];
        const int deg   = (int)counts[seg];
        degtot += deg;
        if (deg == 0) continue;

        const u16* qb = QB + (size_t)node * 256;
        const u32 qv  = *(const u32*)(qb + j0);
        const u32 bv2 = *(const u32*)(qb + 128 + j0);
        const float q0 = bflo(qv) * 0.25f, q1 = bfhi(qv) * 0.25f;  // fold PHD^-0.5
        const float b0 = bflo(bv2), b1 = bfhi(bv2);

        int e = 0;
        for (; e + 4 <= deg; e += 4) {
            u32 kv[4], av[4];
            #pragma unroll
            for (int u = 0; u < 4; ++u) {
                const int src = __builtin_amdgcn_readfirstlane((int)edata[start + e + u]);
                const u16* ka = KA + (size_t)src * 256;     // one 512 B region/edge
                kv[u] = *(const u32*)(ka + j0);
                av[u] = *(const u32*)(ka + 128 + j0);
            }
            #pragma unroll
            for (int u = 0; u < 4; ++u) {
                float d = q0 * bflo(kv[u]) + q1 * bfhi(kv[u]);
                d += __shfl_xor(d, 1);
                d += __shfl_xor(d, 2);
                d += __shfl_xor(d, 4);
                const float ex = __expf(d);
                acc0 += ex * fmaxf(bflo(av[u]) + b0, 0.f);
                acc1 += ex * fmaxf(bfhi(av[u]) + b1, 0.f);
                den  += ex;
            }
        }
        for (; e < deg; ++e) {
            const int src = __builtin_amdgcn_readfirstlane((int)edata[start + e]);
            const u16* ka = KA + (size_t)src * 256;
            const u32 kv = *(const u32*)(ka + j0);
            const u32 av = *(const u32*)(ka + 128 + j0);
            float d = q0 * bflo(kv) + q1 * bfhi(kv);
            d += __shfl_xor(d, 1);
            d += __shfl_xor(d, 2);
            d += __shfl_xor(d, 4);
            const float ex = __expf(d);
            acc0 += ex * fmaxf(bflo(av) + b0, 0.f);
            acc1 += ex * fmaxf(bfhi(av) + b1, 0.f);
            den  += ex;
        }
    }

    float* op = out + (size_t)node * HID + j0;
    if (mode == 2) {                       // fused: softmax over all 3 types in-register
        const float inv = den > 0.f ? 1.f / den : 0.f;
        float2 o;
        o.x = acc0 * inv;
        o.y = acc1 * inv;
        *(float2*)op = o;
    } else if (mode == 1) {
        const float tot = sumexp[(size_t)node * 8 + h] + den;
        const float inv = tot > 0.f ? 1.f / tot : 0.f;
        float2 o = *(float2*)op;
        o.x = (o.x + acc0) * inv;
        o.y = (o.y + acc1) * inv;
        *(float2*)op = o;
    } else {
        if (degtot == 0) return;
        float2 o = *(float2*)op;
        o.x += acc0; o.y += acc1;
        *(float2*)op = o;
        if ((lane & 7) == 0) sumexp[(size_t)node * 8 + h] += den;
    }
}

extern "C" void kernel_launch(void* const* d_in, const int* in_sizes, int n_in,
                              void* d_out, int out_size, void* d_ws, size_t ws_size,
                              hipStream_t stream)
{
    const float* x  = (const float*)d_in[0];
    const int* a0   = (const int*)d_in[1];
    const int* a1   = (const int*)d_in[2];
    const int* a2   = (const int*)d_in[3];
    const float* Wq = (const float*)d_in[4];
    const float* Wk = (const float*)d_in[5];
    const float* Wm = (const float*)d_in[6];
    const float* bm = (const float*)d_in[7];
    float* out = (float*)d_out;

    // ws layout; fused path: 6 combined planes (153.6 MB), fallback: 2 (51.2 MB).
    const size_t planeB = (size_t)PLANE * sizeof(u16);       // 25.6 MB
    const size_t fixedB = 12800000 + 393216 + 3 * 600000 + 4096 + 3000000 + 1600000;
    const int fused = (ws_size >= 6 * planeB + fixedB) ? 1 : 0;
    const int npl = fused ? 6 : 2;

    char* p = (char*)d_ws;
    u16* P        = (u16*)p;            p += (size_t)npl * planeB;
    u16* Xbf      = (u16*)p;            p += 12800000;
    u16* Wtb      = (u16*)p;            p += 393216;
    u32* counts   = (u32*)p;            p += 600000;
    u32* offsets  = (u32*)p;            p += 600000;
    u32* cursors  = (u32*)p;            p += 600000;
    u32* bsum     = (u32*)p;            p += 4096;
    u32* edata    = (u32*)p;            p += 3000000;
    float* sumexp = (float*)p;

    hipMemsetAsync(counts, 0, (size_t)NSEG * sizeof(u32), stream);
    if (!fused) {
        hipMemsetAsync(out,    0, (size_t)NN * HID * sizeof(float), stream);
        hipMemsetAsync(sumexp, 0, (size_t)NN * 8 * sizeof(float), stream);
    }

    prep_kernel<<<7018 + (NT * NE + 255) / 256, 256, 0, stream>>>(
        x, Wq, Wk, Wm, Xbf, Wtb, a0, a1, a2, counts);
    scan1_kernel<<<NB1, 256, 0, stream>>>(counts, bsum);
    scan2_kernel<<<1, 1024, 0, stream>>>(bsum);
    scan3_kernel<<<NB1, 256, 0, stream>>>(counts, bsum, offsets, cursors);
    scatter_kernel<<<(NT * NE + 255) / 256, 256, 0, stream>>>(a0, a1, a2, cursors, edata);

    const int gx = (NN + 127) / 128;    // 391
    const int gb = (NN + 3) / 4;        // 12500
    if (fused) {
        gemm_kernel<<<dim3(gx, 12), 256, 0, stream>>>(Xbf, Wtb, bm, P, 0, 1);
        gather_kernel<<<gb, 256, 0, stream>>>(P, offsets, counts, edata,
                                              out, sumexp, 0, 3, 2, 1);
    } else {
        for (int t = 0; t < NT; ++t) {
            gemm_kernel<<<dim3(gx, 4), 256, 0, stream>>>(Xbf, Wtb, bm, P, t, 0);
            gather_kernel<<<gb, 256, 0, stream>>>(P, offsets, counts, edata,
                                                  out, sumexp, t, 1, t == 2 ? 1 : 0, 0);
        }
    }
}